// Round 15
// baseline (211.816 us; speedup 1.0000x reference)
//
#include <hip/hip_runtime.h>
#include <cstdint>
#include <cstddef>

#define E 32
#define Bsz 64
#define Lsz 2048
#define JCHUNK 128
#define NCH (Lsz / JCHUNK)   // 16
#define VSTR 136             // V^T LDS row stride (halfs): 272B = 17*16B aligned; reads pack banks optimally

typedef float f32x4 __attribute__((ext_vector_type(4)));
typedef float f32x16 __attribute__((ext_vector_type(16)));
typedef __bf16 bf16x8 __attribute__((ext_vector_type(8)));
typedef __bf16 bf16x4 __attribute__((ext_vector_type(4)));
typedef short s16x8 __attribute__((ext_vector_type(8)));
typedef short s16x4 __attribute__((ext_vector_type(4)));
typedef unsigned short u16;

typedef __attribute__((address_space(3))) unsigned int as3_u32;
typedef __attribute__((address_space(1))) const unsigned int as1_u32;

__device__ inline u16 f2bf(float f) {
    union { float f; unsigned u; } x; x.f = f;
    unsigned r = x.u + 0x7FFFu + ((x.u >> 16) & 1u);
    return (u16)(r >> 16);
}

__device__ inline float fexp2(float x) {
#if __has_builtin(__builtin_amdgcn_exp2f)
    return __builtin_amdgcn_exp2f(x);
#else
    return exp2f(x);
#endif
}

__device__ inline void glds(const void* g, void* l) {
    __builtin_amdgcn_global_load_lds((as1_u32*)g, (as3_u32*)l, 16, 0, 0);
}

// 32x32x16 bf16: D = A*B + C (A 8 bf16, B 8 bf16, C/D 16 f32)
__device__ inline f32x16 qk_mfma(bf16x8 a, bf16x8 b, f32x16 c) {
#if __has_builtin(__builtin_amdgcn_mfma_f32_32x32x16_bf16)
    return __builtin_amdgcn_mfma_f32_32x32x16_bf16(a, b, c, 0, 0, 0);
#else
    asm volatile("s_nop 1\n\t"
                 "v_mfma_f32_32x32x16_bf16 %0, %1, %2, %0\n\t"
                 "s_nop 7\n\ts_nop 7"
                 : "+v"(c) : "v"(a), "v"(b));
    return c;
#endif
}
// 32x32x8 bf16: D = A*B + C (A 4 bf16, B 4 bf16, C/D 16 f32)
__device__ inline f32x16 pv_mfma8(bf16x4 a, bf16x4 b, f32x16 c) {
#if __has_builtin(__builtin_amdgcn_mfma_f32_32x32x8_bf16)
    return __builtin_amdgcn_mfma_f32_32x32x8_bf16(a, b, c, 0, 0, 0);
#elif __has_builtin(__builtin_amdgcn_mfma_f32_32x32x8bf16_1k)
    return __builtin_amdgcn_mfma_f32_32x32x8bf16_1k(
        __builtin_bit_cast(s16x4, a), __builtin_bit_cast(s16x4, b), c, 0, 0, 0);
#else
    asm volatile("s_nop 1\n\t"
                 "v_mfma_f32_32x32x8_bf16 %0, %1, %2, %0\n\t"
                 "s_nop 7\n\ts_nop 7"
                 : "+v"(c) : "v"(a), "v"(b));
    return c;
#endif
}

// ---------------- Full PSF mask: M[i][j] = bilinear(i,j) / sqrt(E) * log2(e), bf16 ----------------
__global__ __launch_bounds__(256) void mask_kernel(u16* __restrict__ M) {
    int g = blockIdx.x * 256 + threadIdx.x;
    int i = g >> 11, j = g & 2047;
    const float scale = 21.0f / 2048.0f;
    float si = fmaxf((i + 0.5f) * scale - 0.5f, 0.f);
    float sj = fmaxf((j + 0.5f) * scale - 0.5f, 0.f);
    int i0 = (int)si; float fi = si - (float)i0;
    int j0 = (int)sj; float fj = sj - (float)j0;
    int i0c = min(i0, 20), i1c = min(i0 + 1, 20);
    int j0c = min(j0, 20), j1c = min(j0 + 1, 20);
    int d00 = abs(i0c - j0c), d01 = abs(i0c - j1c), d10 = abs(i1c - j0c), d11 = abs(i1c - j1c);
    float t00 = __expf(-0.125f * (float)(d00 * d00));
    float t01 = __expf(-0.125f * (float)(d01 * d01));
    float t10 = __expf(-0.125f * (float)(d10 * d10));
    float t11 = __expf(-0.125f * (float)(d11 * d11));
    float m = (1.f - fi) * ((1.f - fj) * t00 + fj * t01)
            + fi * ((1.f - fj) * t10 + fj * t11);
    m = m * (0.17677669529663687f * 1.4426950408889634f / 5.0132563952f);
    M[g] = f2bf(m);
}

// ---------------- QKV: x[B][E][L] f32 -> Q,K [B][L][E] bf16, Vt [B][E][L] bf16 ----------------
__global__ __launch_bounds__(256) void qkv_kernel(const float* __restrict__ x,
        const float* __restrict__ Wqkv, const float* __restrict__ bqkv,
        u16* __restrict__ Q, u16* __restrict__ K, u16* __restrict__ Vt) {
    int g = blockIdx.x * 256 + threadIdx.x;
    int b = g >> 11, l = g & 2047;
    float xr[E];
    #pragma unroll
    for (int c = 0; c < E; ++c) xr[c] = x[((size_t)b * E + c) * Lsz + l];

    #pragma unroll
    for (int part = 0; part < 2; ++part) {
        u16* dst = (part == 0) ? Q : K;
        s16x8 pk[4];
        #pragma unroll
        for (int e = 0; e < E; ++e) {
            int o = part * E + e;
            float acc = bqkv[o];
            #pragma unroll
            for (int c = 0; c < E; ++c) acc += xr[c] * Wqkv[o * E + c];
            pk[e >> 3][e & 7] = (short)f2bf(acc);
        }
        s16x8* dp = (s16x8*)(dst + ((size_t)b * Lsz + l) * E);
        #pragma unroll
        for (int q8 = 0; q8 < 4; ++q8) dp[q8] = pk[q8];
    }
    #pragma unroll
    for (int e = 0; e < E; ++e) {
        int o = 2 * E + e;
        float acc = bqkv[o];
        #pragma unroll
        for (int c = 0; c < E; ++c) acc += xr[c] * Wqkv[o * E + c];
        Vt[((size_t)b * E + e) * Lsz + l] = f2bf(acc);
    }
}

// ---------------- Flash attention v11: 32x32 MFMA family, 32 q-rows/wave ----------------
// 1024 blocks (B x L/128) x 256 threads (4 waves x 32 q). LDS 33792B:
//   K [2][128 rows][64B] swizzled at 0; V^T [2][32 e][VSTR]h at byte 16384.
// QK: S^T = mfma_32x32x16(K, Q) (C: col=q=lane&31, row j=(r&3)+8(r>>2)+4hi - HW-verified).
// PV: C-regs [4g..4g+3] ARE the 32x32x8 A-frag (k=4hi+e) -> O[q][e] with no cross-lane.
// Normalization deferred to oproj via Dsum (O's q is reg-indexed; dividing here needs shuffles).
__global__ __launch_bounds__(256, 4) void attn_kernel(const u16* __restrict__ Q,
        const u16* __restrict__ Kg, const u16* __restrict__ Vt,
        const u16* __restrict__ M, float* __restrict__ O, float* __restrict__ Dsum) {
    extern __shared__ char smem[];
    int blk = blockIdx.x;
    int b = blk >> 4;
    int qblk = blk & 15;
    int tid = threadIdx.x;
    int wave = tid >> 6, lane = tid & 63;
    int lq = lane & 31, hi = lane >> 5;
    int qbase = qblk * 128 + wave * 32;

    const size_t bLE = (size_t)b * Lsz * E;
    // Q as QK B-fragment (col=q=lane&31): k-step0 = k[hi*8..+7], k-step1 = +16
    const u16* qp = Q + bLE + (size_t)(qbase + lq) * E + hi * 8;
    bf16x8 qf0 = *(const bf16x8*)(qp);
    bf16x8 qf1 = *(const bf16x8*)(qp + 16);
    const u16* mrow = M + (size_t)(qbase + lq) * Lsz + hi * 4;

    // K staging (glds, pre-swizzled source): LDS slot s of row holds K[row][s ^ (row&3)]
    const char* kcbase = (const char*)(Kg + bLE);
    int krow = tid >> 2, ks4 = tid & 3;
    int ksrc = krow * 64 + ((ks4 ^ (krow & 3)) << 4);   // rows 0..63; +4096 for rows 64..127
    u16* smem_h = (u16*)smem;
    const int VBASE = 8192;       // halfs
    const int VBUF = 32 * VSTR;   // 4352 halfs per buffer

    // V^T staging (reg-staged): thread (ev, sv) covers j = sv*8..+7 and +64
    const u16* vtb = Vt + bLE;
    int ev = tid >> 3, sv = tid & 7;
    size_t vg = (size_t)ev * Lsz + sv * 8;
    int vw = VBASE + ev * VSTR + sv * 8;

    f32x16 o = {};
    float dsum = 0.f;

#define TILE(jt) do { \
    int kr_ = (jt) * 32 + lq; \
    int sw_ = kr_ & 3; \
    const u16* kp_ = smem_h + buf * 4096 + kr_ * 32; \
    bf16x8 ka0 = *(const bf16x8*)(kp_ + (((hi) ^ sw_) << 3)); \
    bf16x8 ka1 = *(const bf16x8*)(kp_ + (((2 + hi) ^ sw_) << 3)); \
    f32x16 zc = {}; \
    f32x16 s_ = qk_mfma(ka1, qf1, qk_mfma(ka0, qf0, zc)); \
    const u16* mr_ = mrow + jco + (jt) * 32; \
    bf16x4 mm0 = *(const bf16x4*)(mr_); \
    bf16x4 mm1 = *(const bf16x4*)(mr_ + 8); \
    bf16x4 mm2 = *(const bf16x4*)(mr_ + 16); \
    bf16x4 mm3 = *(const bf16x4*)(mr_ + 24); \
    bf16x4 pa0, pa1, pa2, pa3; \
    _Pragma("unroll") for (int c = 0; c < 4; ++c) { \
        float p = fexp2(s_[c]      * (float)mm0[c]); dsum += p; pa0[c] = (__bf16)p; } \
    _Pragma("unroll") for (int c = 0; c < 4; ++c) { \
        float p = fexp2(s_[4 + c]  * (float)mm1[c]); dsum += p; pa1[c] = (__bf16)p; } \
    _Pragma("unroll") for (int c = 0; c < 4; ++c) { \
        float p = fexp2(s_[8 + c]  * (float)mm2[c]); dsum += p; pa2[c] = (__bf16)p; } \
    _Pragma("unroll") for (int c = 0; c < 4; ++c) { \
        float p = fexp2(s_[12 + c] * (float)mm3[c]); dsum += p; pa3[c] = (__bf16)p; } \
    const u16* vp_ = smem_h + VBASE + buf * VBUF + lq * VSTR + (jt) * 32 + hi * 4; \
    bf16x4 vf0 = *(const bf16x4*)(vp_); \
    bf16x4 vf1 = *(const bf16x4*)(vp_ + 8); \
    bf16x4 vf2 = *(const bf16x4*)(vp_ + 16); \
    bf16x4 vf3 = *(const bf16x4*)(vp_ + 24); \
    o = pv_mfma8(pa0, vf0, o); \
    o = pv_mfma8(pa1, vf1, o); \
    o = pv_mfma8(pa2, vf2, o); \
    o = pv_mfma8(pa3, vf3, o); \
} while (0)

    int buf = 0;
    {   // prologue: stage chunk 0
        glds(kcbase + ksrc, smem + wave * 1024);
        glds(kcbase + ksrc + 4096, smem + 4096 + wave * 1024);
        s16x8 va = *(const s16x8*)(vtb + vg);
        s16x8 vb = *(const s16x8*)(vtb + vg + 64);
        *(s16x8*)(smem_h + vw) = va;
        *(s16x8*)(smem_h + vw + 64) = vb;
        __syncthreads();
    }
    #pragma unroll 1
    for (int jc = 0; jc < NCH; ++jc) {
        s16x8 va = {}, vb = {};
        if (jc + 1 < NCH) {   // issue next chunk's loads early (glds K; V -> regs)
            const char* kc = kcbase + (size_t)(jc + 1) * 8192;
            glds(kc + ksrc, smem + (buf ^ 1) * 8192 + wave * 1024);
            glds(kc + ksrc + 4096, smem + (buf ^ 1) * 8192 + 4096 + wave * 1024);
            va = *(const s16x8*)(vtb + vg + (size_t)(jc + 1) * JCHUNK);
            vb = *(const s16x8*)(vtb + vg + (size_t)(jc + 1) * JCHUNK + 64);
        }
        const int jco = jc * JCHUNK;
        __builtin_amdgcn_s_setprio(1);
        TILE(0); TILE(1); TILE(2); TILE(3);
        __builtin_amdgcn_s_setprio(0);
        if (jc + 1 < NCH) {   // write-late (T14)
            int vwd = vw + (buf ^ 1) * VBUF;
            *(s16x8*)(smem_h + vwd) = va;
            *(s16x8*)(smem_h + vwd + 64) = vb;
        }
        __syncthreads();
        buf ^= 1;
    }
#undef TILE

    // denominator: lane holds sum over its hi's 16 j-rows for q=lq; combine the two hi halves
    dsum += __shfl_xor(dsum, 32);
    if (lane < 32) Dsum[(size_t)b * Lsz + qbase + lane] = dsum;
    // O (un-normalized): lane holds O[q=(r&3)+8(r>>2)+4hi][e=lq]
    float* obase = O + ((size_t)b * Lsz + qbase) * E + lq;
    #pragma unroll
    for (int r = 0; r < 16; ++r) {
        int qr = (r & 3) + 8 * (r >> 2) + 4 * hi;
        obase[(size_t)qr * E] = o[r];
    }
}

// ---------------- Output projection: O raw [B][L][E] f32 / Dsum -> y[B][E][L] f32 ----------------
__global__ __launch_bounds__(256) void oproj_kernel(const float* __restrict__ O,
        const float* __restrict__ Dsum,
        const float* __restrict__ Wout, const float* __restrict__ bout,
        float* __restrict__ y) {
    int g = blockIdx.x * 256 + threadIdx.x;
    int b = g >> 11, l = g & 2047;
    float inv = 1.0f / Dsum[(size_t)b * Lsz + l];
    float orow[E];
    const float* src = O + ((size_t)b * Lsz + l) * E;
    #pragma unroll
    for (int e = 0; e < E; e += 4) {
        f32x4 t = *(const f32x4*)(src + e);
        orow[e] = t[0] * inv; orow[e + 1] = t[1] * inv;
        orow[e + 2] = t[2] * inv; orow[e + 3] = t[3] * inv;
    }
    #pragma unroll
    for (int c = 0; c < E; ++c) {
        float acc = bout[c];
        #pragma unroll
        for (int e = 0; e < E; ++e) acc += orow[e] * Wout[c * E + e];
        y[((size_t)b * E + c) * Lsz + l] = acc;
    }
}

extern "C" void kernel_launch(void* const* d_in, const int* in_sizes, int n_in,
                              void* d_out, int out_size, void* d_ws, size_t ws_size,
                              hipStream_t stream) {
    const float* x    = (const float*)d_in[0];
    const float* Wqkv = (const float*)d_in[1];
    const float* bqkv = (const float*)d_in[2];
    const float* Wout = (const float*)d_in[3];
    const float* bout = (const float*)d_in[4];
    float* y = (float*)d_out;

    char* ws = (char*)d_ws;
    const size_t szQ = (size_t)Bsz * Lsz * E * sizeof(u16);   // 8.39 MB
    const size_t szM = (size_t)Lsz * Lsz * sizeof(u16);       // 8.39 MB
    const size_t szO = (size_t)Bsz * Lsz * E * sizeof(float); // 16.78 MB
    u16* Q    = (u16*)(ws);
    u16* K    = (u16*)(ws + szQ);
    u16* Vt   = (u16*)(ws + 2 * szQ);
    u16* M    = (u16*)(ws + 3 * szQ);
    float* O  = (float*)(ws + 3 * szQ + szM);
    float* Ds = (float*)(ws + 3 * szQ + szM + szO);           // 512 KB

    const int lds_bytes = 16384 + 2 * (32 * VSTR) * 2;        // 33792

    hipLaunchKernelGGL(mask_kernel, dim3((Lsz * Lsz) / 256), dim3(256), 0, stream, M);
    hipLaunchKernelGGL(qkv_kernel, dim3((Bsz * Lsz) / 256), dim3(256), 0, stream,
                       x, Wqkv, bqkv, Q, K, Vt);
    hipLaunchKernelGGL(attn_kernel, dim3(Bsz * (Lsz / 128)), dim3(256), lds_bytes, stream,
                       Q, K, Vt, M, O, Ds);
    hipLaunchKernelGGL(oproj_kernel, dim3((Bsz * Lsz) / 256), dim3(256), 0, stream,
                       O, Ds, Wout, bout, y);
}

// Round 16
// 202.000 us; speedup vs baseline: 1.0486x; 1.0486x over previous
//
#include <hip/hip_runtime.h>
#include <cstdint>
#include <cstddef>

#define E 32
#define Bsz 64
#define Lsz 2048
#define JCHUNK 64
#define NCH (Lsz / JCHUNK)   // 32
#define VSTR 68              // halfs: word-stride 34 == 2 (mod 32) -> 2-way bank alias (free)
#define VBUF (32 * VSTR)     // halfs per V buffer

typedef float f32x2 __attribute__((ext_vector_type(2)));
typedef float f32x4 __attribute__((ext_vector_type(4)));
typedef float f32x16 __attribute__((ext_vector_type(16)));
typedef __bf16 bf16x8 __attribute__((ext_vector_type(8)));
typedef __bf16 bf16x4 __attribute__((ext_vector_type(4)));
typedef short s16x8 __attribute__((ext_vector_type(8)));
typedef short s16x4 __attribute__((ext_vector_type(4)));
typedef unsigned int u32x4 __attribute__((ext_vector_type(4)));
typedef unsigned short u16;

typedef __attribute__((address_space(3))) unsigned int as3_u32;
typedef __attribute__((address_space(1))) const unsigned int as1_u32;

__device__ inline u16 f2bf(float f) {
    union { float f; unsigned u; } x; x.f = f;
    unsigned r = x.u + 0x7FFFu + ((x.u >> 16) & 1u);
    return (u16)(r >> 16);
}
__device__ inline float u2f(unsigned u) {
    union { unsigned u; float f; } x; x.u = u; return x.f;
}

__device__ inline void glds(const void* g, void* l) {
    __builtin_amdgcn_global_load_lds((as1_u32*)g, (as3_u32*)l, 16, 0, 0);
}

// 32x32x16 bf16 (A 8 bf16, B 8 bf16, C/D 16 f32)
__device__ inline f32x16 qk_mfma(bf16x8 a, bf16x8 b, f32x16 c) {
#if __has_builtin(__builtin_amdgcn_mfma_f32_32x32x16_bf16)
    return __builtin_amdgcn_mfma_f32_32x32x16_bf16(a, b, c, 0, 0, 0);
#else
    asm volatile("s_nop 1\n\tv_mfma_f32_32x32x16_bf16 %0, %1, %2, %0\n\ts_nop 7\n\ts_nop 7"
                 : "+v"(c) : "v"(a), "v"(b));
    return c;
#endif
}
// 32x32x8 bf16 (A 4 bf16, B 4 bf16, C/D 16 f32)
__device__ inline f32x16 pv_mfma8(bf16x4 a, bf16x4 b, f32x16 c) {
#if __has_builtin(__builtin_amdgcn_mfma_f32_32x32x8_bf16)
    return __builtin_amdgcn_mfma_f32_32x32x8_bf16(a, b, c, 0, 0, 0);
#elif __has_builtin(__builtin_amdgcn_mfma_f32_32x32x8bf16_1k)
    return __builtin_amdgcn_mfma_f32_32x32x8bf16_1k(
        __builtin_bit_cast(s16x4, a), __builtin_bit_cast(s16x4, b), c, 0, 0, 0);
#else
    asm volatile("s_nop 1\n\tv_mfma_f32_32x32x8_bf16 %0, %1, %2, %0\n\ts_nop 7\n\ts_nop 7"
                 : "+v"(c) : "v"(a), "v"(b));
    return c;
#endif
}

// ---------------- PSF mask in MFMA-fragment layout, NATURAL scale ----------------
// Mf[qt 64][jt 64][lane 64][reg 16] bf16: element = m(i,j)/sqrt(E) with
// i = qt*32 + (lane&31), j = jt*32 + (r&3) + 8*(r>>2) + 4*(lane>>5)  (32x32 C-layout).
__global__ __launch_bounds__(256) void mask_kernel(u16* __restrict__ Mf) {
    int g = blockIdx.x * 256 + threadIdx.x;        // 0 .. 2^22-1
    int r = g & 15, lane = (g >> 4) & 63, jt = (g >> 10) & 63, qt = g >> 16;
    int i = qt * 32 + (lane & 31);
    int j = jt * 32 + (r & 3) + 8 * ((r >> 2) & 3) + 4 * (lane >> 5);
    const float scale = 21.0f / 2048.0f;
    float si = fmaxf((i + 0.5f) * scale - 0.5f, 0.f);
    float sj = fmaxf((j + 0.5f) * scale - 0.5f, 0.f);
    int i0 = (int)si; float fi = si - (float)i0;
    int j0 = (int)sj; float fj = sj - (float)j0;
    int i0c = min(i0, 20), i1c = min(i0 + 1, 20);
    int j0c = min(j0, 20), j1c = min(j0 + 1, 20);
    int d00 = abs(i0c - j0c), d01 = abs(i0c - j1c), d10 = abs(i1c - j0c), d11 = abs(i1c - j1c);
    float t00 = __expf(-0.125f * (float)(d00 * d00));
    float t01 = __expf(-0.125f * (float)(d01 * d01));
    float t10 = __expf(-0.125f * (float)(d10 * d10));
    float t11 = __expf(-0.125f * (float)(d11 * d11));
    float m = (1.f - fi) * ((1.f - fj) * t00 + fj * t01)
            + fi * ((1.f - fj) * t10 + fj * t11);
    m = m * (0.17677669529663687f / 5.0132563952f);   // /sqrt(32) / Z  (natural scale)
    Mf[g] = f2bf(m);
}

// ---------------- QKV: x[B][E][L] f32 -> Q,K [B][L][E] bf16, Vt [B][E][L] bf16 ----------------
__global__ __launch_bounds__(256) void qkv_kernel(const float* __restrict__ x,
        const float* __restrict__ Wqkv, const float* __restrict__ bqkv,
        u16* __restrict__ Q, u16* __restrict__ K, u16* __restrict__ Vt) {
    int g = blockIdx.x * 256 + threadIdx.x;
    int b = g >> 11, l = g & 2047;
    float xr[E];
    #pragma unroll
    for (int c = 0; c < E; ++c) xr[c] = x[((size_t)b * E + c) * Lsz + l];

    #pragma unroll
    for (int part = 0; part < 2; ++part) {
        u16* dst = (part == 0) ? Q : K;
        s16x8 pk[4];
        #pragma unroll
        for (int e = 0; e < E; ++e) {
            int o = part * E + e;
            float acc = bqkv[o];
            #pragma unroll
            for (int c = 0; c < E; ++c) acc += xr[c] * Wqkv[o * E + c];
            pk[e >> 3][e & 7] = (short)f2bf(acc);
        }
        s16x8* dp = (s16x8*)(dst + ((size_t)b * Lsz + l) * E);
        #pragma unroll
        for (int q8 = 0; q8 < 4; ++q8) dp[q8] = pk[q8];
    }
    #pragma unroll
    for (int e = 0; e < E; ++e) {
        int o = 2 * E + e;
        float acc = bqkv[o];
        #pragma unroll
        for (int c = 0; c < E; ++c) acc += xr[c] * Wqkv[o * E + c];
        Vt[((size_t)b * E + e) * Lsz + l] = f2bf(acc);
    }
}

// ---------------- Flash attention v12: poly-exp, fragment-mask reg-prefetch ----------------
// 1024 blocks (B x L/128) x 256 threads (4 waves x 32 q). 32 chunks of 64 j (2 tiles).
// QK/PV layouts identical to v11 (verified). Mask: fragment-layout bf16, prefetched a
// full chunk ahead into registers; exp replaced by cubic poly on f32x2 (packed fp32).
__global__ __launch_bounds__(256, 4) void attn_kernel(const u16* __restrict__ Q,
        const u16* __restrict__ Kg, const u16* __restrict__ Vt,
        const u16* __restrict__ Mf, float* __restrict__ O, float* __restrict__ Dsum) {
    extern __shared__ char smem[];
    int blk = blockIdx.x;
    int b = blk >> 4;
    int qblk = blk & 15;
    int tid = threadIdx.x;
    int wave = tid >> 6, lane = tid & 63;
    int lq = lane & 31, hi = lane >> 5;
    int qbase = qblk * 128 + wave * 32;
    int qt = qblk * 4 + wave;                      // global 32-row q-tile index

    const size_t bLE = (size_t)b * Lsz * E;
    const u16* qp = Q + bLE + (size_t)(qbase + lq) * E + hi * 8;
    bf16x8 qf0 = *(const bf16x8*)(qp);
    bf16x8 qf1 = *(const bf16x8*)(qp + 16);

    // K staging (pre-swizzled source; LDS slot s holds K[row][s ^ (row&3)], 16B slots)
    const char* kcbase = (const char*)(Kg + bLE);
    int krow = tid >> 2, ks4 = tid & 3;
    int ksrc = krow * 64 + ((ks4 ^ (krow & 3)) << 4);
    u16* smem_h = (u16*)smem;
    u16* vls = smem_h + 4096;                      // V region (halfs); K = halfs 0..4095

    // V^T staging: thread (ev, sv) covers Vt[b][ev][jc*64 + sv*8 .. +7]
    const u16* vtb = Vt + bLE;
    int ev = tid >> 3, sv = tid & 7;
    int vwo = ev * VSTR + sv * 8;

    // mask fragment base for this wave's q-tile
    const u16* mfb = Mf + (size_t)qt * 64 * 1024 + lane * 16;

    f32x16 o = {};
    f32x2 dsum2 = {0.f, 0.f};

#define POLYPAIR(u_, sa_, sb_, dst_, idx_) do { \
    float mlo_ = u2f((u_) << 16); \
    float mhi_ = u2f((u_) & 0xFFFF0000u); \
    f32x2 y_ = {(sa_) * mlo_, (sb_) * mhi_}; \
    f32x2 t_ = y_ * 0.16666667f + 0.5f; \
    t_ = t_ * y_ + 1.0f; \
    f32x2 p_ = t_ * y_ + 1.0f; \
    dsum2 += p_; \
    dst_[idx_] = (__bf16)p_[0]; dst_[(idx_) + 1] = (__bf16)p_[1]; \
} while (0)

#define TILE(jt, mA_, mB_) do { \
    int kr_ = (jt) * 32 + lq; \
    const u16* kp_ = smem_h + buf * 2048 + kr_ * 32; \
    bf16x8 ka0 = *(const bf16x8*)(kp_ + (((hi) ^ (kr_ & 3)) << 3)); \
    bf16x8 ka1 = *(const bf16x8*)(kp_ + (((2 + hi) ^ (kr_ & 3)) << 3)); \
    f32x16 zc = {}; \
    f32x16 s_ = qk_mfma(ka1, qf1, qk_mfma(ka0, qf0, zc)); \
    u32x4 ua_ = __builtin_bit_cast(u32x4, mA_); \
    u32x4 ub_ = __builtin_bit_cast(u32x4, mB_); \
    bf16x4 pa0, pa1, pa2, pa3; \
    POLYPAIR(ua_[0], s_[0],  s_[1],  pa0, 0); \
    POLYPAIR(ua_[1], s_[2],  s_[3],  pa0, 2); \
    POLYPAIR(ua_[2], s_[4],  s_[5],  pa1, 0); \
    POLYPAIR(ua_[3], s_[6],  s_[7],  pa1, 2); \
    POLYPAIR(ub_[0], s_[8],  s_[9],  pa2, 0); \
    POLYPAIR(ub_[1], s_[10], s_[11], pa2, 2); \
    POLYPAIR(ub_[2], s_[12], s_[13], pa3, 0); \
    POLYPAIR(ub_[3], s_[14], s_[15], pa3, 2); \
    const u16* vp_ = vls + buf * VBUF + lq * VSTR + (jt) * 32 + hi * 4; \
    bf16x4 vf0 = *(const bf16x4*)(vp_); \
    bf16x4 vf1 = *(const bf16x4*)(vp_ + 8); \
    bf16x4 vf2 = *(const bf16x4*)(vp_ + 16); \
    bf16x4 vf3 = *(const bf16x4*)(vp_ + 24); \
    o = pv_mfma8(pa0, vf0, o); \
    o = pv_mfma8(pa1, vf1, o); \
    o = pv_mfma8(pa2, vf2, o); \
    o = pv_mfma8(pa3, vf3, o); \
} while (0)

#define BODY(jc_, C0, C1, C2, C3, N0, N1, N2, N3) do { \
    s16x8 va_ = {}; \
    int nx_ = (jc_) + 1; \
    if (nx_ < NCH) { \
        glds(kcbase + (size_t)nx_ * 4096 + ksrc, smem + (buf ^ 1) * 4096 + wave * 1024); \
        va_ = *(const s16x8*)(vtb + (size_t)ev * Lsz + nx_ * JCHUNK + sv * 8); \
        const u16* nmp_ = mfb + (size_t)(nx_ * 2) * 1024; \
        N0 = *(const s16x8*)(nmp_); \
        N1 = *(const s16x8*)(nmp_ + 8); \
        N2 = *(const s16x8*)(nmp_ + 1024); \
        N3 = *(const s16x8*)(nmp_ + 1024 + 8); \
    } \
    __builtin_amdgcn_s_setprio(1); \
    TILE(0, C0, C1); \
    TILE(1, C2, C3); \
    __builtin_amdgcn_s_setprio(0); \
    if (nx_ < NCH) { \
        u16* vd_ = vls + (buf ^ 1) * VBUF + vwo; \
        *(s16x4*)(vd_)     = __builtin_bit_cast(s16x4, (s16x4){va_[0], va_[1], va_[2], va_[3]}); \
        *(s16x4*)(vd_ + 4) = __builtin_bit_cast(s16x4, (s16x4){va_[4], va_[5], va_[6], va_[7]}); \
    } \
    __syncthreads(); \
    buf ^= 1; \
} while (0)

    s16x8 A0 = {}, A1 = {}, A2 = {}, A3 = {}, B0 = {}, B1 = {}, B2 = {}, B3 = {};
    int buf = 0;
    {   // prologue: stage chunk 0 + load its mask set
        glds(kcbase + ksrc, smem + wave * 1024);
        s16x8 va = *(const s16x8*)(vtb + (size_t)ev * Lsz + sv * 8);
        u16* vd = vls + vwo;
        *(s16x4*)(vd)     = __builtin_bit_cast(s16x4, (s16x4){va[0], va[1], va[2], va[3]});
        *(s16x4*)(vd + 4) = __builtin_bit_cast(s16x4, (s16x4){va[4], va[5], va[6], va[7]});
        A0 = *(const s16x8*)(mfb);
        A1 = *(const s16x8*)(mfb + 8);
        A2 = *(const s16x8*)(mfb + 1024);
        A3 = *(const s16x8*)(mfb + 1024 + 8);
        __syncthreads();
    }
    #pragma unroll 1
    for (int jc = 0; jc < NCH; jc += 2) {
        BODY(jc,     A0, A1, A2, A3, B0, B1, B2, B3);
        BODY(jc + 1, B0, B1, B2, B3, A0, A1, A2, A3);
    }
#undef BODY
#undef TILE
#undef POLYPAIR

    // denominator: lane's partial over its hi's j rows for q=lq; combine hi halves
    float dsum = dsum2[0] + dsum2[1];
    dsum += __shfl_xor(dsum, 32);
    if (lane < 32) Dsum[(size_t)b * Lsz + qbase + lane] = dsum;
    // O (un-normalized): lane holds O[q=(r&3)+8(r>>2)+4hi][e=lq]  (v11-verified)
    float* obase = O + ((size_t)b * Lsz + qbase) * E + lq;
    #pragma unroll
    for (int r = 0; r < 16; ++r) {
        int qr = (r & 3) + 8 * (r >> 2) + 4 * hi;
        obase[(size_t)qr * E] = o[r];
    }
}

// ---------------- Output projection: O raw [B][L][E] f32 / Dsum -> y[B][E][L] f32 ----------------
__global__ __launch_bounds__(256) void oproj_kernel(const float* __restrict__ O,
        const float* __restrict__ Dsum,
        const float* __restrict__ Wout, const float* __restrict__ bout,
        float* __restrict__ y) {
    int g = blockIdx.x * 256 + threadIdx.x;
    int b = g >> 11, l = g & 2047;
    float inv = 1.0f / Dsum[(size_t)b * Lsz + l];
    float orow[E];
    const float* src = O + ((size_t)b * Lsz + l) * E;
    #pragma unroll
    for (int e = 0; e < E; e += 4) {
        f32x4 t = *(const f32x4*)(src + e);
        orow[e] = t[0] * inv; orow[e + 1] = t[1] * inv;
        orow[e + 2] = t[2] * inv; orow[e + 3] = t[3] * inv;
    }
    #pragma unroll
    for (int c = 0; c < E; ++c) {
        float acc = bout[c];
        #pragma unroll
        for (int e = 0; e < E; ++e) acc += orow[e] * Wout[c * E + e];
        y[((size_t)b * E + c) * Lsz + l] = acc;
    }
}

extern "C" void kernel_launch(void* const* d_in, const int* in_sizes, int n_in,
                              void* d_out, int out_size, void* d_ws, size_t ws_size,
                              hipStream_t stream) {
    const float* x    = (const float*)d_in[0];
    const float* Wqkv = (const float*)d_in[1];
    const float* bqkv = (const float*)d_in[2];
    const float* Wout = (const float*)d_in[3];
    const float* bout = (const float*)d_in[4];
    float* y = (float*)d_out;

    char* ws = (char*)d_ws;
    const size_t szQ = (size_t)Bsz * Lsz * E * sizeof(u16);   // 8.39 MB
    const size_t szM = (size_t)Lsz * Lsz * sizeof(u16);       // 8.39 MB (Mf)
    const size_t szO = (size_t)Bsz * Lsz * E * sizeof(float); // 16.78 MB
    u16* Q    = (u16*)(ws);
    u16* K    = (u16*)(ws + szQ);
    u16* Vt   = (u16*)(ws + 2 * szQ);
    u16* Mf   = (u16*)(ws + 3 * szQ);
    float* O  = (float*)(ws + 3 * szQ + szM);
    float* Ds = (float*)(ws + 3 * szQ + szM + szO);           // 512 KB

    const int lds_bytes = 8192 + 2 * VBUF * 2;                // K dbuf + V dbuf = 16896

    hipLaunchKernelGGL(mask_kernel, dim3((Lsz * Lsz) / 256), dim3(256), 0, stream, Mf);
    hipLaunchKernelGGL(qkv_kernel, dim3((Bsz * Lsz) / 256), dim3(256), 0, stream,
                       x, Wqkv, bqkv, Q, K, Vt);
    hipLaunchKernelGGL(attn_kernel, dim3(Bsz * (Lsz / 128)), dim3(256), lds_bytes, stream,
                       Q, K, Vt, Mf, O, Ds);
    hipLaunchKernelGGL(oproj_kernel, dim3((Bsz * Lsz) / 256), dim3(256), 0, stream,
                       O, Ds, Wout, bout, y);
}

// Round 17
// 170.902 us; speedup vs baseline: 1.2394x; 1.1820x over previous
//
#include <hip/hip_runtime.h>
#include <cstdint>
#include <cstddef>

#define E 32
#define Bsz 64
#define Lsz 2048
#define JCHUNK 128
#define NCH (Lsz / JCHUNK)   // 16
#define JBCH 4               // band halfwidth in chunks (512 j); m<1.2e-3 outside -> P~1
#define VSTR 132             // V^T LDS row stride (halfs): word-stride 66 == 2 mod 32 -> uniform 2-way
#define VBUF (32 * VSTR)     // halfs per V buffer

typedef float f32x4 __attribute__((ext_vector_type(4)));
typedef float f32x16 __attribute__((ext_vector_type(16)));
typedef __bf16 bf16x8 __attribute__((ext_vector_type(8)));
typedef __bf16 bf16x4 __attribute__((ext_vector_type(4)));
typedef short s16x8 __attribute__((ext_vector_type(8)));
typedef short s16x4 __attribute__((ext_vector_type(4)));
typedef unsigned short u16;

typedef __attribute__((address_space(3))) unsigned int as3_u32;
typedef __attribute__((address_space(1))) const unsigned int as1_u32;

__device__ inline u16 f2bf(float f) {
    union { float f; unsigned u; } x; x.f = f;
    unsigned r = x.u + 0x7FFFu + ((x.u >> 16) & 1u);
    return (u16)(r >> 16);
}
__device__ inline float bf2f(u16 h) {
    union { unsigned u; float f; } x; x.u = ((unsigned)h) << 16;
    return x.f;
}

__device__ inline float fexp2(float x) {
#if __has_builtin(__builtin_amdgcn_exp2f)
    return __builtin_amdgcn_exp2f(x);
#else
    return exp2f(x);
#endif
}

__device__ inline void glds(const void* g, void* l) {
    __builtin_amdgcn_global_load_lds((as1_u32*)g, (as3_u32*)l, 16, 0, 0);
}

// 32x32x16 bf16 (A 8 bf16, B 8 bf16, C/D 16 f32)
__device__ inline f32x16 qk_mfma(bf16x8 a, bf16x8 b, f32x16 c) {
#if __has_builtin(__builtin_amdgcn_mfma_f32_32x32x16_bf16)
    return __builtin_amdgcn_mfma_f32_32x32x16_bf16(a, b, c, 0, 0, 0);
#else
    asm volatile("s_nop 1\n\tv_mfma_f32_32x32x16_bf16 %0, %1, %2, %0\n\ts_nop 7\n\ts_nop 7"
                 : "+v"(c) : "v"(a), "v"(b));
    return c;
#endif
}
// 32x32x8 bf16 (A 4 bf16, B 4 bf16, C/D 16 f32)
__device__ inline f32x16 pv_mfma8(bf16x4 a, bf16x4 b, f32x16 c) {
#if __has_builtin(__builtin_amdgcn_mfma_f32_32x32x8_bf16)
    return __builtin_amdgcn_mfma_f32_32x32x8_bf16(a, b, c, 0, 0, 0);
#elif __has_builtin(__builtin_amdgcn_mfma_f32_32x32x8bf16_1k)
    return __builtin_amdgcn_mfma_f32_32x32x8bf16_1k(
        __builtin_bit_cast(s16x4, a), __builtin_bit_cast(s16x4, b), c, 0, 0, 0);
#else
    asm volatile("s_nop 1\n\tv_mfma_f32_32x32x8_bf16 %0, %1, %2, %0\n\ts_nop 7\n\ts_nop 7"
                 : "+v"(c) : "v"(a), "v"(b));
    return c;
#endif
}

// ---------------- Full PSF mask: M[i][j] = bilinear(i,j)/sqrt(E)*log2(e), bf16 ----------------
__global__ __launch_bounds__(256) void mask_kernel(u16* __restrict__ M) {
    int g = blockIdx.x * 256 + threadIdx.x;
    int i = g >> 11, j = g & 2047;
    const float scale = 21.0f / 2048.0f;
    float si = fmaxf((i + 0.5f) * scale - 0.5f, 0.f);
    float sj = fmaxf((j + 0.5f) * scale - 0.5f, 0.f);
    int i0 = (int)si; float fi = si - (float)i0;
    int j0 = (int)sj; float fj = sj - (float)j0;
    int i0c = min(i0, 20), i1c = min(i0 + 1, 20);
    int j0c = min(j0, 20), j1c = min(j0 + 1, 20);
    int d00 = abs(i0c - j0c), d01 = abs(i0c - j1c), d10 = abs(i1c - j0c), d11 = abs(i1c - j1c);
    float t00 = __expf(-0.125f * (float)(d00 * d00));
    float t01 = __expf(-0.125f * (float)(d01 * d01));
    float t10 = __expf(-0.125f * (float)(d10 * d10));
    float t11 = __expf(-0.125f * (float)(d11 * d11));
    float m = (1.f - fi) * ((1.f - fj) * t00 + fj * t01)
            + fi * ((1.f - fj) * t10 + fj * t11);
    m = m * (0.17677669529663687f * 1.4426950408889634f / 5.0132563952f);
    M[g] = f2bf(m);
}

// ---------------- QKV: x[B][E][L] f32 -> Q,K [B][L][E] bf16, Vt [B][E][L] bf16 ----------------
__global__ __launch_bounds__(256) void qkv_kernel(const float* __restrict__ x,
        const float* __restrict__ Wqkv, const float* __restrict__ bqkv,
        u16* __restrict__ Q, u16* __restrict__ K, u16* __restrict__ Vt) {
    int g = blockIdx.x * 256 + threadIdx.x;
    int b = g >> 11, l = g & 2047;
    float xr[E];
    #pragma unroll
    for (int c = 0; c < E; ++c) xr[c] = x[((size_t)b * E + c) * Lsz + l];

    #pragma unroll
    for (int part = 0; part < 2; ++part) {
        u16* dst = (part == 0) ? Q : K;
        s16x8 pk[4];
        #pragma unroll
        for (int e = 0; e < E; ++e) {
            int o = part * E + e;
            float acc = bqkv[o];
            #pragma unroll
            for (int c = 0; c < E; ++c) acc += xr[c] * Wqkv[o * E + c];
            pk[e >> 3][e & 7] = (short)f2bf(acc);
        }
        s16x8* dp = (s16x8*)(dst + ((size_t)b * Lsz + l) * E);
        #pragma unroll
        for (int q8 = 0; q8 < 4; ++q8) dp[q8] = pk[q8];
    }
    #pragma unroll
    for (int e = 0; e < E; ++e) {
        int o = 2 * E + e;
        float acc = bqkv[o];
        #pragma unroll
        for (int c = 0; c < E; ++c) acc += xr[c] * Wqkv[o * E + c];
        Vt[((size_t)b * E + e) * Lsz + l] = f2bf(acc);
    }
}

// ---------------- per-chunk V column sums: Vcs[b][ch][e] = sum_{j in ch} V[j][e] ----------------
__global__ __launch_bounds__(64) void sumv_kernel(const u16* __restrict__ Vt,
                                                  float* __restrict__ Vcs) {
    int bi = blockIdx.x;              // 2048 = 64 b x 32 e
    int b = bi >> 5, e = bi & 31;
    int lane = threadIdx.x;
    const u16* src = Vt + ((size_t)b * E + e) * Lsz;
    #pragma unroll 1
    for (int c = 0; c < NCH; ++c) {
        float s = bf2f(src[c * 128 + lane]) + bf2f(src[c * 128 + 64 + lane]);
        s += __shfl_xor(s, 1);  s += __shfl_xor(s, 2);  s += __shfl_xor(s, 4);
        s += __shfl_xor(s, 8);  s += __shfl_xor(s, 16); s += __shfl_xor(s, 32);
        if (lane == 0) Vcs[((size_t)b * NCH + c) * 32 + e] = s;
    }
}

// ---------------- Flash attention v13: band-limited, 32x32 MFMA (v11 layouts) ----------------
// 1024 blocks (B x L/128) x 256 threads (4 waves x 32 q). Band = chunks [qblk-4, qblk+5).
// Outside band: P = 1 exactly-to-tolerance -> O_num += (sum_out V[e]), den += #outside.
// K swizzle sigma=(row>>1)&3 -> uniform 8 words/bank on b128 reads (v11's row&3 was 2x).
__global__ __launch_bounds__(256, 4) void attn_kernel(const u16* __restrict__ Q,
        const u16* __restrict__ Kg, const u16* __restrict__ Vt,
        const u16* __restrict__ M, const float* __restrict__ Vcs,
        float* __restrict__ O, float* __restrict__ Dsum) {
    extern __shared__ char smem[];
    int blk = blockIdx.x;
    int b = blk >> 4;
    int qblk = blk & 15;
    int tid = threadIdx.x;
    int wave = tid >> 6, lane = tid & 63;
    int lq = lane & 31, hi = lane >> 5;
    int qbase = qblk * 128 + wave * 32;

    const int jlo = max(0, qblk - JBCH);
    const int jhi = min(NCH, qblk + 1 + JBCH);

    const size_t bLE = (size_t)b * Lsz * E;
    const u16* qp = Q + bLE + (size_t)(qbase + lq) * E + hi * 8;
    bf16x8 qf0 = *(const bf16x8*)(qp);
    bf16x8 qf1 = *(const bf16x8*)(qp + 16);
    const u16* mrow = M + (size_t)(qbase + lq) * Lsz + hi * 4;

    // K staging: LDS slot p of row holds K[row][p ^ ((row>>1)&3)] (16B slots)
    const char* kcbase = (const char*)(Kg + bLE);
    int krow = tid >> 2, ks4 = tid & 3;
    int ksrc = krow * 64 + ((ks4 ^ ((krow >> 1) & 3)) << 4);
    u16* smem_h = (u16*)smem;
    u16* vls = smem_h + 8192;     // V region; K = halfs 0..8191 (2 bufs x 4096)

    // V^T staging: thread (ev, sv) covers Vt[b][ev][jc*128 + sv*8 (+64)]
    const u16* vtb = Vt + bLE;
    int ev = tid >> 3, sv = tid & 7;
    size_t vg = (size_t)ev * Lsz + sv * 8;
    int vwo = ev * VSTR + sv * 8;

    f32x16 o = {};
    float dsum = 0.f;

#define TILE(jt) do { \
    int kr_ = (jt) * 32 + lq; \
    int sw_ = (kr_ >> 1) & 3; \
    const u16* kp_ = smem_h + buf * 4096 + kr_ * 32; \
    bf16x8 ka0 = *(const bf16x8*)(kp_ + (((hi) ^ sw_) << 3)); \
    bf16x8 ka1 = *(const bf16x8*)(kp_ + (((2 + hi) ^ sw_) << 3)); \
    f32x16 zc = {}; \
    f32x16 s_ = qk_mfma(ka1, qf1, qk_mfma(ka0, qf0, zc)); \
    const u16* mr_ = mrow + jco + (jt) * 32; \
    bf16x4 mm0 = *(const bf16x4*)(mr_); \
    bf16x4 mm1 = *(const bf16x4*)(mr_ + 8); \
    bf16x4 mm2 = *(const bf16x4*)(mr_ + 16); \
    bf16x4 mm3 = *(const bf16x4*)(mr_ + 24); \
    bf16x4 pa0, pa1, pa2, pa3; \
    _Pragma("unroll") for (int c = 0; c < 4; ++c) { \
        float p = fexp2(s_[c]      * (float)mm0[c]); dsum += p; pa0[c] = (__bf16)p; } \
    _Pragma("unroll") for (int c = 0; c < 4; ++c) { \
        float p = fexp2(s_[4 + c]  * (float)mm1[c]); dsum += p; pa1[c] = (__bf16)p; } \
    _Pragma("unroll") for (int c = 0; c < 4; ++c) { \
        float p = fexp2(s_[8 + c]  * (float)mm2[c]); dsum += p; pa2[c] = (__bf16)p; } \
    _Pragma("unroll") for (int c = 0; c < 4; ++c) { \
        float p = fexp2(s_[12 + c] * (float)mm3[c]); dsum += p; pa3[c] = (__bf16)p; } \
    const u16* vp_ = vls + buf * VBUF + lq * VSTR + (jt) * 32 + hi * 4; \
    bf16x4 vf0 = *(const bf16x4*)(vp_); \
    bf16x4 vf1 = *(const bf16x4*)(vp_ + 8); \
    bf16x4 vf2 = *(const bf16x4*)(vp_ + 16); \
    bf16x4 vf3 = *(const bf16x4*)(vp_ + 24); \
    o = pv_mfma8(pa0, vf0, o); \
    o = pv_mfma8(pa1, vf1, o); \
    o = pv_mfma8(pa2, vf2, o); \
    o = pv_mfma8(pa3, vf3, o); \
} while (0)

    int buf = 0;
    {   // prologue: stage first band chunk
        const char* kc = kcbase + (size_t)jlo * 8192;
        glds(kc + ksrc, smem + wave * 1024);
        glds(kc + ksrc + 4096, smem + 4096 + wave * 1024);
        s16x8 va = *(const s16x8*)(vtb + vg + (size_t)jlo * JCHUNK);
        s16x8 vb = *(const s16x8*)(vtb + vg + (size_t)jlo * JCHUNK + 64);
        u16* vd = vls + vwo;
        *(s16x4*)(vd)          = (s16x4){va[0], va[1], va[2], va[3]};
        *(s16x4*)(vd + 4)      = (s16x4){va[4], va[5], va[6], va[7]};
        *(s16x4*)(vd + 64)     = (s16x4){vb[0], vb[1], vb[2], vb[3]};
        *(s16x4*)(vd + 64 + 4) = (s16x4){vb[4], vb[5], vb[6], vb[7]};
        __syncthreads();
    }
    #pragma unroll 1
    for (int jc = jlo; jc < jhi; ++jc) {
        s16x8 va = {}, vb = {};
        if (jc + 1 < jhi) {
            const char* kc = kcbase + (size_t)(jc + 1) * 8192;
            glds(kc + ksrc, smem + (buf ^ 1) * 8192 + wave * 1024);
            glds(kc + ksrc + 4096, smem + (buf ^ 1) * 8192 + 4096 + wave * 1024);
            va = *(const s16x8*)(vtb + vg + (size_t)(jc + 1) * JCHUNK);
            vb = *(const s16x8*)(vtb + vg + (size_t)(jc + 1) * JCHUNK + 64);
        }
        const int jco = jc * JCHUNK;
        __builtin_amdgcn_s_setprio(1);
        TILE(0); TILE(1); TILE(2); TILE(3);
        __builtin_amdgcn_s_setprio(0);
        if (jc + 1 < jhi) {
            u16* vd = vls + (buf ^ 1) * VBUF + vwo;
            *(s16x4*)(vd)          = (s16x4){va[0], va[1], va[2], va[3]};
            *(s16x4*)(vd + 4)      = (s16x4){va[4], va[5], va[6], va[7]};
            *(s16x4*)(vd + 64)     = (s16x4){vb[0], vb[1], vb[2], vb[3]};
            *(s16x4*)(vd + 64 + 4) = (s16x4){vb[4], vb[5], vb[6], vb[7]};
        }
        __syncthreads();
        buf ^= 1;
    }
#undef TILE

    // outside-band V sum for e=lq and the outside count
    float vout = 0.f;
    #pragma unroll 1
    for (int c = 0; c < NCH; ++c)
        if (c < jlo || c >= jhi) vout += Vcs[((size_t)b * NCH + c) * 32 + lq];
    // denominator: combine hi halves, then add outside count
    dsum += __shfl_xor(dsum, 32);
    dsum += (float)(JCHUNK * (NCH - (jhi - jlo)));
    if (lane < 32) Dsum[(size_t)b * Lsz + qbase + lane] = dsum;
    // O (un-normalized): lane holds O[q=(r&3)+8(r>>2)+4hi][e=lq]; outside adds vout to all q
    float* obase = O + ((size_t)b * Lsz + qbase) * E + lq;
    #pragma unroll
    for (int r = 0; r < 16; ++r) {
        int qr = (r & 3) + 8 * (r >> 2) + 4 * hi;
        obase[(size_t)qr * E] = o[r] + vout;
    }
}

// ---------------- Output projection: O raw [B][L][E] f32 / Dsum -> y[B][E][L] f32 ----------------
__global__ __launch_bounds__(256) void oproj_kernel(const float* __restrict__ O,
        const float* __restrict__ Dsum,
        const float* __restrict__ Wout, const float* __restrict__ bout,
        float* __restrict__ y) {
    int g = blockIdx.x * 256 + threadIdx.x;
    int b = g >> 11, l = g & 2047;
    float inv = 1.0f / Dsum[(size_t)b * Lsz + l];
    float orow[E];
    const float* src = O + ((size_t)b * Lsz + l) * E;
    #pragma unroll
    for (int e = 0; e < E; e += 4) {
        f32x4 t = *(const f32x4*)(src + e);
        orow[e] = t[0] * inv; orow[e + 1] = t[1] * inv;
        orow[e + 2] = t[2] * inv; orow[e + 3] = t[3] * inv;
    }
    #pragma unroll
    for (int c = 0; c < E; ++c) {
        float acc = bout[c];
        #pragma unroll
        for (int e = 0; e < E; ++e) acc += orow[e] * Wout[c * E + e];
        y[((size_t)b * E + c) * Lsz + l] = acc;
    }
}

extern "C" void kernel_launch(void* const* d_in, const int* in_sizes, int n_in,
                              void* d_out, int out_size, void* d_ws, size_t ws_size,
                              hipStream_t stream) {
    const float* x    = (const float*)d_in[0];
    const float* Wqkv = (const float*)d_in[1];
    const float* bqkv = (const float*)d_in[2];
    const float* Wout = (const float*)d_in[3];
    const float* bout = (const float*)d_in[4];
    float* y = (float*)d_out;

    char* ws = (char*)d_ws;
    const size_t szQ  = (size_t)Bsz * Lsz * E * sizeof(u16);   // 8.39 MB
    const size_t szM  = (size_t)Lsz * Lsz * sizeof(u16);       // 8.39 MB
    const size_t szO  = (size_t)Bsz * Lsz * E * sizeof(float); // 16.78 MB
    const size_t szDs = (size_t)Bsz * Lsz * sizeof(float);     // 512 KB
    u16* Q     = (u16*)(ws);
    u16* K     = (u16*)(ws + szQ);
    u16* Vt    = (u16*)(ws + 2 * szQ);
    u16* M     = (u16*)(ws + 3 * szQ);
    float* O   = (float*)(ws + 3 * szQ + szM);
    float* Ds  = (float*)(ws + 3 * szQ + szM + szO);
    float* Vcs = (float*)(ws + 3 * szQ + szM + szO + szDs);    // 128 KB

    const int lds_bytes = 16384 + 2 * VBUF * 2;                // K dbuf + V dbuf = 33280

    hipLaunchKernelGGL(mask_kernel, dim3((Lsz * Lsz) / 256), dim3(256), 0, stream, M);
    hipLaunchKernelGGL(qkv_kernel, dim3((Bsz * Lsz) / 256), dim3(256), 0, stream,
                       x, Wqkv, bqkv, Q, K, Vt);
    hipLaunchKernelGGL(sumv_kernel, dim3(Bsz * 32), dim3(64), 0, stream, Vt, Vcs);
    hipLaunchKernelGGL(attn_kernel, dim3(Bsz * (Lsz / 128)), dim3(256), lds_bytes, stream,
                       Q, K, Vt, M, Vcs, O, Ds);
    hipLaunchKernelGGL(oproj_kernel, dim3((Bsz * Lsz) / 256), dim3(256), 0, stream,
                       O, Ds, Wout, bout, y);
}